// Round 2
// baseline (10579.580 us; speedup 1.0000x reference)
//
#include <hip/hip_runtime.h>
#include <cstdint>
#include <cstddef>

// MultiLayerLSTM on gfx950 — round 6: layer-wavefront pipeline with a SINGLE
// merged grid-wait per round and fence-free agent-coherent h traffic.
// All 4 layers run concurrently on 256 blocks (64/layer, 1/CU), skew 1 round:
// at round r, layer l does t = r - l. Input flag (layer l-1) and own-peer flag
// thresholds are both r, so ONE poll covers both matmuls. h slabs move via
// relaxed agent-scope atomics (sc1: write-through / read-through at the
// coherence point), so no buffer_inv / buffer_wbl2 fences are needed in the
// serial chain -- __syncthreads' vmcnt(0) drain before the flag store is the
// only release mechanism.
// L=4 layers, B=64, T=256, D=H=1024.

#define LL 4
#define BB 64
#define TT 256
#define DD 1024
#define HH 1024
#define FOURH 4096
#define APAD 1032   // padded LDS row stride (bf16 elems)

typedef __bf16 bf16;
typedef __bf16 bf16x8 __attribute__((ext_vector_type(8)));
typedef __bf16 bf16x4 __attribute__((ext_vector_type(4)));
typedef __bf16 bf16x2 __attribute__((ext_vector_type(2)));
typedef float f32x4 __attribute__((ext_vector_type(4)));

__device__ __forceinline__ void async_load16(const void* g, void* l) {
    __builtin_amdgcn_global_load_lds(
        (const __attribute__((address_space(1))) unsigned int*)g,
        (__attribute__((address_space(3))) unsigned int*)l,
        16, 0, 0);
}

__device__ __forceinline__ f32x4 mfma_bf16(bf16x8 a, bf16x8 b, f32x4 c) {
    return __builtin_amdgcn_mfma_f32_16x16x32_bf16(a, b, c, 0, 0, 0);
}

__device__ __forceinline__ float fsig(float x) {
    return 1.f / (1.f + __expf(-x));
}
__device__ __forceinline__ float ftanh(float x) {
    x = fminf(10.f, fmaxf(-10.f, x));
    float e = __expf(2.f * x);
    return (e - 1.f) / (e + 1.f);
}

// ---------------- f32 -> bf16 convert (vectorized x4) ----------------
__global__ void cvt_f32_bf16(const float* __restrict__ in, bf16* __restrict__ out, int n4) {
    int i = blockIdx.x * blockDim.x + threadIdx.x;
    if (i < n4) {
        float4 v = ((const float4*)in)[i];
        bf16x4 o = { (bf16)v.x, (bf16)v.y, (bf16)v.z, (bf16)v.w };
        ((bf16x4*)out)[i] = o;
    }
}

// x [B][T][D] f32 -> x_bf [T][B][D] bf16. One block per (b,t) row.
__global__ __launch_bounds__(256) void cvt_x_transpose(
    const float* __restrict__ x, bf16* __restrict__ out) {
    int bx = blockIdx.x;           // = b*TT + t
    int b = bx >> 8, t = bx & 255;
    int tid = threadIdx.x;
    float4 v = ((const float4*)(x + (size_t)bx * DD))[tid];
    bf16x4 o = { (bf16)v.x, (bf16)v.y, (bf16)v.z, (bf16)v.w };
    ((bf16x4*)(out + ((size_t)(t * BB + b)) * DD))[tid] = o;
}

// ---------------- GEMM: C[M,N] = A[M,K] @ W[N,K]^T + bias[N] ----------------
// REMAP: output row m = t*B+b is written to row b*TT+t (f32 logits in [B][T]).
template <bool OUT_BF16, bool REMAP>
__global__ __launch_bounds__(256) void gemm_bt(
    const bf16* __restrict__ A, const bf16* __restrict__ W,
    const float* __restrict__ bias, void* __restrict__ Cout,
    int M, int N, int K)
{
    __shared__ bf16 As[128 * 32];
    __shared__ bf16 Bs[128 * 32];
    const int tid = threadIdx.x;
    const int wave = tid >> 6, lane = tid & 63;
    const int lmod = lane & 15, lhalf = lane >> 4;
    const int m0 = blockIdx.y * 128, n0 = blockIdx.x * 128;
    const int wr = (wave >> 1) * 64, wc = (wave & 1) * 64;

    f32x4 acc[4][4] = {};

    const int arow = tid >> 2;
    const int acol = (tid & 3) * 8;
    const bf16* Ab  = A + (size_t)(m0 + arow) * K + acol;
    const bf16* Ab2 = A + (size_t)(m0 + 64 + arow) * K + acol;
    const bf16* Wb  = W + (size_t)(n0 + arow) * K + acol;
    const bf16* Wb2 = W + (size_t)(n0 + 64 + arow) * K + acol;

    for (int kc = 0; kc < K; kc += 32) {
        async_load16(Ab + kc,  &As[tid * 8]);
        async_load16(Ab2 + kc, &As[2048 + tid * 8]);
        async_load16(Wb + kc,  &Bs[tid * 8]);
        async_load16(Wb2 + kc, &Bs[2048 + tid * 8]);
        __syncthreads();

        bf16x8 af[4], bfr[4];
#pragma unroll
        for (int mt = 0; mt < 4; mt++)
            af[mt] = *(const bf16x8*)&As[(wr + mt * 16 + lmod) * 32 + lhalf * 8];
#pragma unroll
        for (int nt = 0; nt < 4; nt++)
            bfr[nt] = *(const bf16x8*)&Bs[(wc + nt * 16 + lmod) * 32 + lhalf * 8];
#pragma unroll
        for (int mt = 0; mt < 4; mt++)
#pragma unroll
            for (int nt = 0; nt < 4; nt++)
                acc[mt][nt] = mfma_bf16(af[mt], bfr[nt], acc[mt][nt]);
        __syncthreads();
    }

#pragma unroll
    for (int mt = 0; mt < 4; mt++) {
#pragma unroll
        for (int nt = 0; nt < 4; nt++) {
            int n = n0 + wc + nt * 16 + lmod;
            float bv = bias[n];
#pragma unroll
            for (int r = 0; r < 4; r++) {
                int m = m0 + wr + mt * 16 + lhalf * 4 + r;
                int orow = REMAP ? ((m & 63) * TT + (m >> 6)) : m;
                float v = acc[mt][nt][r] + bv;
                if (OUT_BF16)
                    ((bf16*)Cout)[(size_t)orow * N + n] = (bf16)v;
                else
                    ((float*)Cout)[(size_t)orow * N + n] = v;
            }
        }
    }
}

// ---------------- Pipelined persistent LSTM kernel (all layers) ----------------
// 256 blocks x 256 threads, 1 block/CU. layer = bid>>6, block owns 16 hidden
// units (j0). Wave w = gate w; Wih and Whh row-slices both persistent
// (VGPR/AGPR). Per round r (t = r-layer): ONE merged poll (inflags>=r AND
// myflags>=r) -> stage h_{l-1,t} (coherent loads) -> Wih MFMA -> restage
// h_{l,t-1} -> Whh MFMA (accumulate) -> gate exchange -> cell update ->
// publish h via agent-scope atomic stores -> syncthreads (vmcnt drain) ->
// flag store. No cache fences anywhere in the loop.
__global__ __launch_bounds__(256, 1) void lstm_pipe(
    const bf16* __restrict__ x_bf,     // [T*B, D] layer-0 input slabs
    const bf16* __restrict__ h0_all,   // [L, B*H] initial h (bf16)
    const float* __restrict__ c0_all,  // [L, B*H] initial c (f32)
    const bf16* __restrict__ wih,      // [L, 4H, H]
    const bf16* __restrict__ whh,      // [L, 4H, H]
    const float* __restrict__ bias,    // [L, 4H]
    bf16* __restrict__ hseq_base,      // [L, T*B, H]
    float* __restrict__ outH, float* __restrict__ outC,  // [L, B*H]
    int* __restrict__ flags)           // [256], zeroed
{
    __shared__ bf16 As[64 * APAD];       // 132 KB padded A-slab (shared by both matmuls)
    __shared__ float Gs[4 * 64 * 17];    // 17.4 KB gate exchange

    const int tid = threadIdx.x;
    const int wave = tid >> 6, lane = tid & 63;
    const int lmod = lane & 15, lhalf = lane >> 4;
    const int bid = blockIdx.x;
    const int layer = bid >> 6;
    const int j0 = (bid & 63) * 16;

    const size_t SLAB = (size_t)TT * BB * HH;
    const bf16* inseq = (layer == 0) ? x_bf : (hseq_base + (size_t)(layer - 1) * SLAB);
    bf16* hseq = hseq_base + (size_t)layer * SLAB;
    const bf16* h0 = h0_all + (size_t)layer * BB * HH;
    const float* c0 = c0_all + (size_t)layer * BB * HH;
    float* oH = outH + (size_t)layer * BB * HH;
    float* oC = outC + (size_t)layer * BB * HH;
    int* inflags = flags + (layer > 0 ? (layer - 1) * 64 : 0);
    int* myflags = flags + layer * 64;
    const bool needIn = (layer > 0);

    // per-lane gate bias (column = this lane's gate-unit)
    const float bv = bias[layer * FOURH + wave * 1024 + j0 + lmod];

    // persistent weight fragments: wave w = gate w, unit row j0+lmod
    bf16x8 wI[32], wH[32];
    {
        const size_t row = (size_t)layer * FOURH + wave * 1024 + j0 + lmod;
        const bf16* wrI = wih + row * 1024 + lhalf * 8;
        const bf16* wrH = whh + row * 1024 + lhalf * 8;
#pragma unroll
        for (int kc = 0; kc < 32; kc++) {
            wI[kc] = *(const bf16x8*)(wrI + kc * 32);
            wH[kc] = *(const bf16x8*)(wrH + kc * 32);
        }
    }

    // persistent cell state: thread owns (m, jj) and (m, jj+1) at p=q*512+tid*2
    float2 creg[2];
#pragma unroll
    for (int q = 0; q < 2; q++) {
        int p = q * 512 + tid * 2;
        creg[q] = *(const float2*)&c0[(p >> 4) * 1024 + j0 + (p & 15)];
    }

    for (int t = 0; t < TT; t++) {
        const int r = t + layer;

        // ---- ONE merged wait: input peers (>=r) and own peers (>=r) ----
        if (t > 0 || needIn) {
            if (wave == 0) {
                const bool nOwn = (t > 0);
                for (;;) {
                    int a = needIn ? __hip_atomic_load(&inflags[lane], __ATOMIC_RELAXED,
                                                       __HIP_MEMORY_SCOPE_AGENT)
                                   : 0x7fffffff;
                    int b = nOwn ? __hip_atomic_load(&myflags[lane], __ATOMIC_RELAXED,
                                                     __HIP_MEMORY_SCOPE_AGENT)
                                 : 0x7fffffff;
                    if (__all((a >= r) && (b >= r))) break;
                }
            }
            __syncthreads();
        }

        // ---- stage input slab h_{l-1,t} (or x) via coherent 8B loads ----
        {
            const bf16* src = inseq + (size_t)t * (BB * HH);
#pragma unroll 16
            for (int i = 0; i < 64; i++) {
                unsigned long long v = __hip_atomic_load(
                    (const unsigned long long*)(src + i * 1024 + tid * 4),
                    __ATOMIC_RELAXED, __HIP_MEMORY_SCOPE_AGENT);
                *(unsigned long long*)&As[i * APAD + tid * 4] = v;
            }
        }
        __syncthreads();

        // ---- input projection MFMA ----
        f32x4 acc[4] = {};
#pragma unroll
        for (int kc = 0; kc < 32; kc++) {
#pragma unroll
            for (int mt = 0; mt < 4; mt++) {
                bf16x8 a = *(const bf16x8*)&As[(mt * 16 + lmod) * APAD + kc * 32 + lhalf * 8];
                acc[mt] = mfma_bf16(a, wI[kc], acc[mt]);
            }
        }
        __syncthreads();   // all waves done reading As before restage

        // ---- stage own h_{t-1} slab ----
        {
            const bf16* src = (t == 0) ? h0 : (hseq + (size_t)(t - 1) * BB * HH);
#pragma unroll 16
            for (int i = 0; i < 64; i++) {
                unsigned long long v = __hip_atomic_load(
                    (const unsigned long long*)(src + i * 1024 + tid * 4),
                    __ATOMIC_RELAXED, __HIP_MEMORY_SCOPE_AGENT);
                *(unsigned long long*)&As[i * APAD + tid * 4] = v;
            }
        }
        __syncthreads();

        // ---- recurrent MFMA (accumulates onto input projection) ----
#pragma unroll
        for (int kc = 0; kc < 32; kc++) {
#pragma unroll
            for (int mt = 0; mt < 4; mt++) {
                bf16x8 a = *(const bf16x8*)&As[(mt * 16 + lmod) * APAD + kc * 32 + lhalf * 8];
                acc[mt] = mfma_bf16(a, wH[kc], acc[mt]);
            }
        }

        // park gates (+bias) in LDS for the cross-wave exchange
#pragma unroll
        for (int mt = 0; mt < 4; mt++)
#pragma unroll
            for (int rr = 0; rr < 4; rr++) {
                int m = mt * 16 + lhalf * 4 + rr;
                Gs[(wave * 64 + m) * 17 + lmod] = acc[mt][rr] + bv;
            }
        __syncthreads();

        // fused cell update; publish h via agent-scope atomic 4B stores
        const bool lastt = (t == TT - 1);
#pragma unroll
        for (int q = 0; q < 2; q++) {
            int p = q * 512 + tid * 2;
            int m = p >> 4, jj = p & 15;
            float cv[2], hv[2];
#pragma unroll
            for (int u = 0; u < 2; u++) {
                float gi = Gs[(0 * 64 + m) * 17 + jj + u];
                float gf = Gs[(1 * 64 + m) * 17 + jj + u];
                float gg = Gs[(2 * 64 + m) * 17 + jj + u];
                float go = Gs[(3 * 64 + m) * 17 + jj + u];
                float cprev = u ? creg[q].y : creg[q].x;
                float c = fsig(gf) * cprev + fsig(gi) * ftanh(gg);
                float h = fsig(go) * ftanh(c);
                cv[u] = c; hv[u] = h;
            }
            creg[q].x = cv[0]; creg[q].y = cv[1];
            union { bf16x2 h2; unsigned int u32; } pk;
            pk.h2.x = (bf16)hv[0]; pk.h2.y = (bf16)hv[1];
            __hip_atomic_store(
                (unsigned int*)&hseq[((size_t)(t * BB + m)) * HH + j0 + jj],
                pk.u32, __ATOMIC_RELAXED, __HIP_MEMORY_SCOPE_AGENT);
            if (lastt) {
                *(float2*)&oH[m * 1024 + j0 + jj] = make_float2(hv[0], hv[1]);
                *(float2*)&oC[m * 1024 + j0 + jj] = make_float2(cv[0], cv[1]);
            }
        }

        // publish: __syncthreads drains each wave's vmcnt (stores are at the
        // coherence point), then one flag store. No cache fence needed.
        __syncthreads();
        if (tid == 0) {
            __hip_atomic_store(&flags[bid], r + 1, __ATOMIC_RELAXED,
                               __HIP_MEMORY_SCOPE_AGENT);
        }
    }
}

extern "C" void kernel_launch(void* const* d_in, const int* in_sizes, int n_in,
                              void* d_out, int out_size, void* d_ws, size_t ws_size,
                              hipStream_t stream) {
    const float* x    = (const float*)d_in[0];
    const float* h0   = (const float*)d_in[1];
    const float* c0   = (const float*)d_in[2];
    const float* Wih  = (const float*)d_in[3];
    const float* Whh  = (const float*)d_in[4];
    const float* bias = (const float*)d_in[5];
    const float* Wout = (const float*)d_in[6];
    const float* bout = (const float*)d_in[7];

    // ---- workspace layout (~226.5 MB) ----
    char* p = (char*)d_ws;
    int*  ctrs    = (int*)p;  p += 1024;                             // 256 flags
    bf16* x_bf    = (bf16*)p; p += (size_t)BB * TT * DD * 2;         // 32 MB ([T][B][D])
    bf16* hseq    = (bf16*)p; p += (size_t)LL * BB * TT * HH * 2;    // 128 MB (per-layer slabs)
    bf16* wih_bf  = (bf16*)p; p += (size_t)LL * FOURH * HH * 2;      // 32 MB
    bf16* whh_bf  = (bf16*)p; p += (size_t)LL * FOURH * HH * 2;      // 32 MB
    bf16* wout_bf = (bf16*)p; p += (size_t)DD * HH * 2;              // 2 MB
    bf16* h0_bf   = (bf16*)p; p += (size_t)LL * BB * HH * 2;         // 0.5 MB
    if ((size_t)(p - (char*)d_ws) > ws_size) return;

    hipMemsetAsync(ctrs, 0, 1024, stream);

    // ---- convert inputs to bf16 ----
    cvt_x_transpose<<<BB * TT, 256, 0, stream>>>(x, x_bf);
    {
        struct { const float* in; bf16* out; size_t n; } jobs[4] = {
            { Wih,  wih_bf,  (size_t)LL * FOURH * HH },
            { Whh,  whh_bf,  (size_t)LL * FOURH * HH },
            { Wout, wout_bf, (size_t)DD * HH },
            { h0,   h0_bf,   (size_t)LL * BB * HH },
        };
        for (int j = 0; j < 4; j++) {
            int n4 = (int)(jobs[j].n / 4);
            cvt_f32_bf16<<<(n4 + 255) / 256, 256, 0, stream>>>(jobs[j].in, jobs[j].out, n4);
        }
    }

    float* logits = (float*)d_out;
    float* outH = logits + (size_t)BB * TT * DD;
    float* outC = outH + (size_t)LL * BB * HH;

    // ---- all 4 layers, pipelined, one persistent dispatch ----
    lstm_pipe<<<LL * 64, 256, 0, stream>>>(
        x_bf, h0_bf, c0, wih_bf, whh_bf, bias,
        hseq, outH, outC, ctrs);

    // ---- output projection from layer-3 hidden sequence ----
    dim3 g2(DD / 128, (BB * TT) / 128);
    gemm_bt<false, true><<<g2, 256, 0, stream>>>(
        hseq + (size_t)(LL - 1) * TT * BB * HH, wout_bf, bout, logits,
        BB * TT, DD, HH);
}

// Round 3
// 3217.421 us; speedup vs baseline: 3.2882x; 3.2882x over previous
//
#include <hip/hip_runtime.h>
#include <cstdint>
#include <cstddef>

// MultiLayerLSTM on gfx950 — round 7: layer-wavefront pipeline with
// aggregator + private-mailbox sync (no contended flag polling), fence-free
// write-through h publish (sc1) + CACHED global_load_lds staging (L2-shared),
// and input-matmul-first reordering to hide the recurrence wait.
// 256 blocks (64/layer, 1 block/CU). At round r, layer l does t = r - l.
// L=4 layers, B=64, T=256, D=H=1024.

#define LL 4
#define BB 64
#define TT 256
#define DD 1024
#define HH 1024
#define FOURH 4096
#define APAD 1032   // padded LDS row stride (bf16 elems)

typedef __bf16 bf16;
typedef __bf16 bf16x8 __attribute__((ext_vector_type(8)));
typedef __bf16 bf16x4 __attribute__((ext_vector_type(4)));
typedef __bf16 bf16x2 __attribute__((ext_vector_type(2)));
typedef float f32x4 __attribute__((ext_vector_type(4)));

__device__ __forceinline__ void async_load16(const void* g, void* l) {
    __builtin_amdgcn_global_load_lds(
        (const __attribute__((address_space(1))) unsigned int*)g,
        (__attribute__((address_space(3))) unsigned int*)l,
        16, 0, 0);
}

__device__ __forceinline__ f32x4 mfma_bf16(bf16x8 a, bf16x8 b, f32x4 c) {
    return __builtin_amdgcn_mfma_f32_16x16x32_bf16(a, b, c, 0, 0, 0);
}

__device__ __forceinline__ float fsig(float x) {
    return 1.f / (1.f + __expf(-x));
}
__device__ __forceinline__ float ftanh(float x) {
    x = fminf(10.f, fmaxf(-10.f, x));
    float e = __expf(2.f * x);
    return (e - 1.f) / (e + 1.f);
}

__device__ __forceinline__ int aload(const int* p) {
    return __hip_atomic_load(p, __ATOMIC_RELAXED, __HIP_MEMORY_SCOPE_AGENT);
}
__device__ __forceinline__ void astore(int* p, int v) {
    __hip_atomic_store(p, v, __ATOMIC_RELAXED, __HIP_MEMORY_SCOPE_AGENT);
}

// ---------------- f32 -> bf16 convert (vectorized x4) ----------------
__global__ void cvt_f32_bf16(const float* __restrict__ in, bf16* __restrict__ out, int n4) {
    int i = blockIdx.x * blockDim.x + threadIdx.x;
    if (i < n4) {
        float4 v = ((const float4*)in)[i];
        bf16x4 o = { (bf16)v.x, (bf16)v.y, (bf16)v.z, (bf16)v.w };
        ((bf16x4*)out)[i] = o;
    }
}

// x [B][T][D] f32 -> x_bf [T][B][D] bf16. One block per (b,t) row.
__global__ __launch_bounds__(256) void cvt_x_transpose(
    const float* __restrict__ x, bf16* __restrict__ out) {
    int bx = blockIdx.x;           // = b*TT + t
    int b = bx >> 8, t = bx & 255;
    int tid = threadIdx.x;
    float4 v = ((const float4*)(x + (size_t)bx * DD))[tid];
    bf16x4 o = { (bf16)v.x, (bf16)v.y, (bf16)v.z, (bf16)v.w };
    ((bf16x4*)(out + ((size_t)(t * BB + b)) * DD))[tid] = o;
}

// ---------------- GEMM: C[M,N] = A[M,K] @ W[N,K]^T + bias[N] ----------------
// REMAP: output row m = t*B+b is written to row b*TT+t (f32 logits in [B][T]).
template <bool OUT_BF16, bool REMAP>
__global__ __launch_bounds__(256) void gemm_bt(
    const bf16* __restrict__ A, const bf16* __restrict__ W,
    const float* __restrict__ bias, void* __restrict__ Cout,
    int M, int N, int K)
{
    __shared__ bf16 As[128 * 32];
    __shared__ bf16 Bs[128 * 32];
    const int tid = threadIdx.x;
    const int wave = tid >> 6, lane = tid & 63;
    const int lmod = lane & 15, lhalf = lane >> 4;
    const int m0 = blockIdx.y * 128, n0 = blockIdx.x * 128;
    const int wr = (wave >> 1) * 64, wc = (wave & 1) * 64;

    f32x4 acc[4][4] = {};

    const int arow = tid >> 2;
    const int acol = (tid & 3) * 8;
    const bf16* Ab  = A + (size_t)(m0 + arow) * K + acol;
    const bf16* Ab2 = A + (size_t)(m0 + 64 + arow) * K + acol;
    const bf16* Wb  = W + (size_t)(n0 + arow) * K + acol;
    const bf16* Wb2 = W + (size_t)(n0 + 64 + arow) * K + acol;

    for (int kc = 0; kc < K; kc += 32) {
        async_load16(Ab + kc,  &As[tid * 8]);
        async_load16(Ab2 + kc, &As[2048 + tid * 8]);
        async_load16(Wb + kc,  &Bs[tid * 8]);
        async_load16(Wb2 + kc, &Bs[2048 + tid * 8]);
        __syncthreads();

        bf16x8 af[4], bfr[4];
#pragma unroll
        for (int mt = 0; mt < 4; mt++)
            af[mt] = *(const bf16x8*)&As[(wr + mt * 16 + lmod) * 32 + lhalf * 8];
#pragma unroll
        for (int nt = 0; nt < 4; nt++)
            bfr[nt] = *(const bf16x8*)&Bs[(wc + nt * 16 + lmod) * 32 + lhalf * 8];
#pragma unroll
        for (int mt = 0; mt < 4; mt++)
#pragma unroll
            for (int nt = 0; nt < 4; nt++)
                acc[mt][nt] = mfma_bf16(af[mt], bfr[nt], acc[mt][nt]);
        __syncthreads();
    }

#pragma unroll
    for (int mt = 0; mt < 4; mt++) {
#pragma unroll
        for (int nt = 0; nt < 4; nt++) {
            int n = n0 + wc + nt * 16 + lmod;
            float bv = bias[n];
#pragma unroll
            for (int r = 0; r < 4; r++) {
                int m = m0 + wr + mt * 16 + lhalf * 4 + r;
                int orow = REMAP ? ((m & 63) * TT + (m >> 6)) : m;
                float v = acc[mt][nt][r] + bv;
                if (OUT_BF16)
                    ((bf16*)Cout)[(size_t)orow * N + n] = (bf16)v;
                else
                    ((float*)Cout)[(size_t)orow * N + n] = v;
            }
        }
    }
}

// ---------------- Pipelined persistent LSTM kernel (all layers) ----------------
// Sync protocol (all relaxed agent-scope atomics, ZERO cache fences):
//   flags[bid]  = number of completed steps by block bid (published after the
//                 sc1 write-through h stores are drained by __syncthreads).
//   mbox[bid]   = private 64B line per block: [0]=.own (written by own-layer
//                 aggregator), [1]=.in (written by previous-layer aggregator).
//   Aggregator  = block l*64, wave 0: the ONLY poller of the layer's 64 flags.
//                 At step t>0 it gathers flags>=t then fans out .own=t (own
//                 layer) and .in=t (next layer). After the loop it does one
//                 extra gather (flags>=TT) and fans out .in=TT (deadlock fix
//                 for the consumers' final step).
// Consumers spin single-lane on their private mailbox line only.
// Data coherence: h published via sc1 write-through stores (at L3 before the
// flag); readers use normal CACHED loads — no reader L2 can hold a stale tag
// for a slab (each slab is written once then read once per dispatch), so
// L2-shared fills are safe and no buffer_inv/wbl2 is needed.
// Order per step: [agg gather+fanout | in-wait] -> stage-IN -> MFMA_in ->
// [own-wait] -> stage-OWN -> MFMA_own -> gate exchange -> cell update ->
// publish (sc1) -> flag. The in-side work (~2.6us) hides the own-wait chain.
__global__ __launch_bounds__(256, 1) void lstm_pipe(
    const bf16* __restrict__ x_bf,     // [T*B, D] layer-0 input slabs
    const bf16* __restrict__ h0_all,   // [L, B*H] initial h (bf16)
    const float* __restrict__ c0_all,  // [L, B*H] initial c (f32)
    const bf16* __restrict__ wih,      // [L, 4H, H]
    const bf16* __restrict__ whh,      // [L, 4H, H]
    const float* __restrict__ bias,    // [L, 4H]
    bf16* __restrict__ hseq_base,      // [L, T*B, H]
    float* __restrict__ outH, float* __restrict__ outC,  // [L, B*H]
    int* __restrict__ flags,           // [256] step counters, zeroed
    int* __restrict__ mbox)            // [256*16] 64B-strided mailboxes, zeroed
{
    __shared__ bf16 As[64 * APAD];       // 132 KB padded A-slab (both matmuls)
    __shared__ float Gs[4 * 64 * 17];    // 17.4 KB gate exchange

    const int tid = threadIdx.x;
    const int wave = tid >> 6, lane = tid & 63;
    const int lmod = lane & 15, lhalf = lane >> 4;
    const int bid = blockIdx.x;
    const int layer = bid >> 6;
    const int j0 = (bid & 63) * 16;
    const bool isAgg = ((bid & 63) == 0);

    const size_t SLAB = (size_t)TT * BB * HH;
    const bf16* inseq = (layer == 0) ? x_bf : (hseq_base + (size_t)(layer - 1) * SLAB);
    bf16* hseq = hseq_base + (size_t)layer * SLAB;
    const bf16* h0 = h0_all + (size_t)layer * BB * HH;
    const float* c0 = c0_all + (size_t)layer * BB * HH;
    float* oH = outH + (size_t)layer * BB * HH;
    float* oC = outC + (size_t)layer * BB * HH;

    // per-lane gate bias (column = this lane's gate-unit)
    const float bv = bias[layer * FOURH + wave * 1024 + j0 + lmod];

    // persistent weight fragments: wave w = gate w, unit row j0+lmod
    bf16x8 wI[32], wH[32];
    {
        const size_t row = (size_t)layer * FOURH + wave * 1024 + j0 + lmod;
        const bf16* wrI = wih + row * 1024 + lhalf * 8;
        const bf16* wrH = whh + row * 1024 + lhalf * 8;
#pragma unroll
        for (int kc = 0; kc < 32; kc++) {
            wI[kc] = *(const bf16x8*)(wrI + kc * 32);
            wH[kc] = *(const bf16x8*)(wrH + kc * 32);
        }
    }

    // persistent cell state: thread owns (m, jj) and (m, jj+1) at p=q*512+tid*2
    float2 creg[2];
#pragma unroll
    for (int q = 0; q < 2; q++) {
        int p = q * 512 + tid * 2;
        creg[q] = *(const float2*)&c0[(p >> 4) * 1024 + j0 + (p & 15)];
    }

    // cached 16B wave-level staging into padded LDS (global_load_lds).
    // chunk k = wave*32+i covers (row = k>>1, half = k&1); global offset is
    // linear: wave*16384 + i*512 + lane*8 elems.
    auto stage = [&](const bf16* src) {
#pragma unroll
        for (int i = 0; i < 32; i++) {
            int k = wave * 32 + i;
            int row = k >> 1, half = k & 1;
            async_load16(src + (size_t)row * 1024 + half * 512 + lane * 8,
                         &As[row * APAD + half * 512 + lane * 8]);
        }
    };

    for (int t = 0; t < TT; t++) {
        // ---- round start: aggregator gather+fanout; consumers' in-wait ----
        if (wave == 0) {
            if (isAgg && t > 0) {
                for (;;) {
                    int v = aload(&flags[layer * 64 + lane]);
                    if (__all(v >= t)) break;
                }
                astore(&mbox[(layer * 64 + lane) * 16 + 0], t);
                if (layer < 3)
                    astore(&mbox[((layer + 1) * 64 + lane) * 16 + 1], t);
            }
            if (layer > 0 && lane == 0) {
                while (aload(&mbox[bid * 16 + 1]) < t + 1) {}
            }
        }
        __syncthreads();

        // ---- stage input slab h_{l-1,t} (or x_t), cached + L2-shared ----
        stage(inseq + (size_t)t * (BB * HH));
        __syncthreads();

        // ---- input projection MFMA ----
        f32x4 acc[4] = {};
#pragma unroll
        for (int kc = 0; kc < 32; kc++) {
#pragma unroll
            for (int mt = 0; mt < 4; mt++) {
                bf16x8 a = *(const bf16x8*)&As[(mt * 16 + lmod) * APAD + kc * 32 + lhalf * 8];
                acc[mt] = mfma_bf16(a, wI[kc], acc[mt]);
            }
        }

        // ---- own-peer wait (hidden under the input-side work above) ----
        if (wave == 0 && !isAgg && t > 0 && lane == 0) {
            while (aload(&mbox[bid * 16 + 0]) < t) {}
        }
        __syncthreads();   // all waves done reading As; own-dependency cleared

        // ---- stage own h_{t-1} slab ----
        stage((t == 0) ? h0 : (hseq + (size_t)(t - 1) * BB * HH));
        __syncthreads();

        // ---- recurrent MFMA (accumulates onto input projection) ----
#pragma unroll
        for (int kc = 0; kc < 32; kc++) {
#pragma unroll
            for (int mt = 0; mt < 4; mt++) {
                bf16x8 a = *(const bf16x8*)&As[(mt * 16 + lmod) * APAD + kc * 32 + lhalf * 8];
                acc[mt] = mfma_bf16(a, wH[kc], acc[mt]);
            }
        }

        // park gates (+bias) in LDS for the cross-wave exchange
#pragma unroll
        for (int mt = 0; mt < 4; mt++)
#pragma unroll
            for (int rr = 0; rr < 4; rr++) {
                int m = mt * 16 + lhalf * 4 + rr;
                Gs[(wave * 64 + m) * 17 + lmod] = acc[mt][rr] + bv;
            }
        __syncthreads();

        // fused cell update; publish h via sc1 write-through 4B stores
        const bool lastt = (t == TT - 1);
#pragma unroll
        for (int q = 0; q < 2; q++) {
            int p = q * 512 + tid * 2;
            int m = p >> 4, jj = p & 15;
            float cv[2], hv[2];
#pragma unroll
            for (int u = 0; u < 2; u++) {
                float gi = Gs[(0 * 64 + m) * 17 + jj + u];
                float gf = Gs[(1 * 64 + m) * 17 + jj + u];
                float gg = Gs[(2 * 64 + m) * 17 + jj + u];
                float go = Gs[(3 * 64 + m) * 17 + jj + u];
                float cprev = u ? creg[q].y : creg[q].x;
                float c = fsig(gf) * cprev + fsig(gi) * ftanh(gg);
                float h = fsig(go) * ftanh(c);
                cv[u] = c; hv[u] = h;
            }
            creg[q].x = cv[0]; creg[q].y = cv[1];
            union { bf16x2 h2; unsigned int u32; } pk;
            pk.h2.x = (bf16)hv[0]; pk.h2.y = (bf16)hv[1];
            __hip_atomic_store(
                (unsigned int*)&hseq[((size_t)(t * BB + m)) * HH + j0 + jj],
                pk.u32, __ATOMIC_RELAXED, __HIP_MEMORY_SCOPE_AGENT);
            if (lastt) {
                *(float2*)&oH[m * 1024 + j0 + jj] = make_float2(hv[0], hv[1]);
                *(float2*)&oC[m * 1024 + j0 + jj] = make_float2(cv[0], cv[1]);
            }
        }

        // publish: __syncthreads drains each wave's vmcnt (stores are at the
        // coherence point), then one flag store.
        __syncthreads();
        if (tid == 0) astore(&flags[bid], t + 1);
    }

    // ---- deadlock fix: final .in=TT fanout for the next layer's last step ----
    if (wave == 0 && isAgg && layer < 3) {
        for (;;) {
            int v = aload(&flags[layer * 64 + lane]);
            if (__all(v >= TT)) break;
        }
        astore(&mbox[((layer + 1) * 64 + lane) * 16 + 1], TT);
    }
}

extern "C" void kernel_launch(void* const* d_in, const int* in_sizes, int n_in,
                              void* d_out, int out_size, void* d_ws, size_t ws_size,
                              hipStream_t stream) {
    const float* x    = (const float*)d_in[0];
    const float* h0   = (const float*)d_in[1];
    const float* c0   = (const float*)d_in[2];
    const float* Wih  = (const float*)d_in[3];
    const float* Whh  = (const float*)d_in[4];
    const float* bias = (const float*)d_in[5];
    const float* Wout = (const float*)d_in[6];
    const float* bout = (const float*)d_in[7];

    // ---- workspace layout (~226.6 MB) ----
    char* p = (char*)d_ws;
    int*  ctrs    = (int*)p;  p += 1024;                             // 256 flags
    int*  mbox    = (int*)p;  p += 256 * 64;                         // 16 KB mailboxes
    bf16* x_bf    = (bf16*)p; p += (size_t)BB * TT * DD * 2;         // 32 MB ([T][B][D])
    bf16* hseq    = (bf16*)p; p += (size_t)LL * BB * TT * HH * 2;    // 128 MB (per-layer slabs)
    bf16* wih_bf  = (bf16*)p; p += (size_t)LL * FOURH * HH * 2;      // 32 MB
    bf16* whh_bf  = (bf16*)p; p += (size_t)LL * FOURH * HH * 2;      // 32 MB
    bf16* wout_bf = (bf16*)p; p += (size_t)DD * HH * 2;              // 2 MB
    bf16* h0_bf   = (bf16*)p; p += (size_t)LL * BB * HH * 2;         // 0.5 MB
    if ((size_t)(p - (char*)d_ws) > ws_size) return;

    hipMemsetAsync(ctrs, 0, 1024 + 256 * 64, stream);

    // ---- convert inputs to bf16 ----
    cvt_x_transpose<<<BB * TT, 256, 0, stream>>>(x, x_bf);
    {
        struct { const float* in; bf16* out; size_t n; } jobs[4] = {
            { Wih,  wih_bf,  (size_t)LL * FOURH * HH },
            { Whh,  whh_bf,  (size_t)LL * FOURH * HH },
            { Wout, wout_bf, (size_t)DD * HH },
            { h0,   h0_bf,   (size_t)LL * BB * HH },
        };
        for (int j = 0; j < 4; j++) {
            int n4 = (int)(jobs[j].n / 4);
            cvt_f32_bf16<<<(n4 + 255) / 256, 256, 0, stream>>>(jobs[j].in, jobs[j].out, n4);
        }
    }

    float* logits = (float*)d_out;
    float* outH = logits + (size_t)BB * TT * DD;
    float* outC = outH + (size_t)LL * BB * HH;

    // ---- all 4 layers, pipelined, one persistent dispatch ----
    lstm_pipe<<<LL * 64, 256, 0, stream>>>(
        x_bf, h0_bf, c0, wih_bf, whh_bf, bias,
        hseq, outH, outC, ctrs, mbox);

    // ---- output projection from layer-3 hidden sequence ----
    dim3 g2(DD / 128, (BB * TT) / 128);
    gemm_bt<false, true><<<g2, 256, 0, stream>>>(
        hseq + (size_t)(LL - 1) * TT * BB * HH, wout_bf, bout, logits,
        BB * TT, DD, HH);
}

// Round 4
// 2297.801 us; speedup vs baseline: 4.6042x; 1.4002x over previous
//
#include <hip/hip_runtime.h>
#include <cstdint>
#include <cstddef>

// MultiLayerLSTM on gfx950 — round 8: K-split wave decomposition.
// Round-7 skeleton (aggregator+mailbox sync, sc1 publish, cached
// global_load_lds staging, in-first ordering) unchanged. The MFMA phase is
// restructured: wave w owns K-slice [w*256,(w+1)*256) x ALL 64 gate-rows
// (4 gates x 16 units), so each A-fragment LDS read feeds 4 MFMAs instead of
// 1 -> LDS A-read traffic drops 4x (1MB -> 256KB per CU-round). Cross-wave
// partial reduction goes through an LDS buffer aliased over the dead A-slab.
// 256 blocks (64/layer, 1 block/CU). At round r, layer l does t = r - l.
// L=4 layers, B=64, T=256, D=H=1024.

#define LL 4
#define BB 64
#define TT 256
#define DD 1024
#define HH 1024
#define FOURH 4096
#define APAD 1032   // padded LDS row stride (bf16 elems)
#define PPAD 68     // padded P row stride (f32 elems): 2-way banks only

typedef __bf16 bf16;
typedef __bf16 bf16x8 __attribute__((ext_vector_type(8)));
typedef __bf16 bf16x4 __attribute__((ext_vector_type(4)));
typedef __bf16 bf16x2 __attribute__((ext_vector_type(2)));
typedef float f32x4 __attribute__((ext_vector_type(4)));

__device__ __forceinline__ void async_load16(const void* g, void* l) {
    __builtin_amdgcn_global_load_lds(
        (const __attribute__((address_space(1))) unsigned int*)g,
        (__attribute__((address_space(3))) unsigned int*)l,
        16, 0, 0);
}

__device__ __forceinline__ f32x4 mfma_bf16(bf16x8 a, bf16x8 b, f32x4 c) {
    return __builtin_amdgcn_mfma_f32_16x16x32_bf16(a, b, c, 0, 0, 0);
}

__device__ __forceinline__ float fsig(float x) {
    return 1.f / (1.f + __expf(-x));
}
__device__ __forceinline__ float ftanh(float x) {
    x = fminf(10.f, fmaxf(-10.f, x));
    float e = __expf(2.f * x);
    return (e - 1.f) / (e + 1.f);
}

__device__ __forceinline__ int aload(const int* p) {
    return __hip_atomic_load(p, __ATOMIC_RELAXED, __HIP_MEMORY_SCOPE_AGENT);
}
__device__ __forceinline__ void astore(int* p, int v) {
    __hip_atomic_store(p, v, __ATOMIC_RELAXED, __HIP_MEMORY_SCOPE_AGENT);
}

// ---------------- f32 -> bf16 convert (vectorized x4) ----------------
__global__ void cvt_f32_bf16(const float* __restrict__ in, bf16* __restrict__ out, int n4) {
    int i = blockIdx.x * blockDim.x + threadIdx.x;
    if (i < n4) {
        float4 v = ((const float4*)in)[i];
        bf16x4 o = { (bf16)v.x, (bf16)v.y, (bf16)v.z, (bf16)v.w };
        ((bf16x4*)out)[i] = o;
    }
}

// x [B][T][D] f32 -> x_bf [T][B][D] bf16. One block per (b,t) row.
__global__ __launch_bounds__(256) void cvt_x_transpose(
    const float* __restrict__ x, bf16* __restrict__ out) {
    int bx = blockIdx.x;           // = b*TT + t
    int b = bx >> 8, t = bx & 255;
    int tid = threadIdx.x;
    float4 v = ((const float4*)(x + (size_t)bx * DD))[tid];
    bf16x4 o = { (bf16)v.x, (bf16)v.y, (bf16)v.z, (bf16)v.w };
    ((bf16x4*)(out + ((size_t)(t * BB + b)) * DD))[tid] = o;
}

// ---------------- GEMM: C[M,N] = A[M,K] @ W[N,K]^T + bias[N] ----------------
// REMAP: output row m = t*B+b is written to row b*TT+t (f32 logits in [B][T]).
template <bool OUT_BF16, bool REMAP>
__global__ __launch_bounds__(256) void gemm_bt(
    const bf16* __restrict__ A, const bf16* __restrict__ W,
    const float* __restrict__ bias, void* __restrict__ Cout,
    int M, int N, int K)
{
    __shared__ bf16 As[128 * 32];
    __shared__ bf16 Bs[128 * 32];
    const int tid = threadIdx.x;
    const int wave = tid >> 6, lane = tid & 63;
    const int lmod = lane & 15, lhalf = lane >> 4;
    const int m0 = blockIdx.y * 128, n0 = blockIdx.x * 128;
    const int wr = (wave >> 1) * 64, wc = (wave & 1) * 64;

    f32x4 acc[4][4] = {};

    const int arow = tid >> 2;
    const int acol = (tid & 3) * 8;
    const bf16* Ab  = A + (size_t)(m0 + arow) * K + acol;
    const bf16* Ab2 = A + (size_t)(m0 + 64 + arow) * K + acol;
    const bf16* Wb  = W + (size_t)(n0 + arow) * K + acol;
    const bf16* Wb2 = W + (size_t)(n0 + 64 + arow) * K + acol;

    for (int kc = 0; kc < K; kc += 32) {
        async_load16(Ab + kc,  &As[tid * 8]);
        async_load16(Ab2 + kc, &As[2048 + tid * 8]);
        async_load16(Wb + kc,  &Bs[tid * 8]);
        async_load16(Wb2 + kc, &Bs[2048 + tid * 8]);
        __syncthreads();

        bf16x8 af[4], bfr[4];
#pragma unroll
        for (int mt = 0; mt < 4; mt++)
            af[mt] = *(const bf16x8*)&As[(wr + mt * 16 + lmod) * 32 + lhalf * 8];
#pragma unroll
        for (int nt = 0; nt < 4; nt++)
            bfr[nt] = *(const bf16x8*)&Bs[(wc + nt * 16 + lmod) * 32 + lhalf * 8];
#pragma unroll
        for (int mt = 0; mt < 4; mt++)
#pragma unroll
            for (int nt = 0; nt < 4; nt++)
                acc[mt][nt] = mfma_bf16(af[mt], bfr[nt], acc[mt][nt]);
        __syncthreads();
    }

#pragma unroll
    for (int mt = 0; mt < 4; mt++) {
#pragma unroll
        for (int nt = 0; nt < 4; nt++) {
            int n = n0 + wc + nt * 16 + lmod;
            float bv = bias[n];
#pragma unroll
            for (int r = 0; r < 4; r++) {
                int m = m0 + wr + mt * 16 + lhalf * 4 + r;
                int orow = REMAP ? ((m & 63) * TT + (m >> 6)) : m;
                float v = acc[mt][nt][r] + bv;
                if (OUT_BF16)
                    ((bf16*)Cout)[(size_t)orow * N + n] = (bf16)v;
                else
                    ((float*)Cout)[(size_t)orow * N + n] = v;
            }
        }
    }
}

// ---------------- Pipelined persistent LSTM kernel (all layers) ----------------
// Sync protocol: round-7 aggregator + private mailboxes, unchanged (proven).
// Compute per round, K-split: wave w holds Wih,Whh rows for all 4 gates x 16
// units over K-slice [w*256,(w+1)*256) (256 VGPRs total). Per A-fragment read
// (mt,kc) the wave issues 4 MFMAs (nt = gate 0..3) -> 4x less LDS A-traffic.
// acc[4][4] partials are reduced across waves via P (f32 [4][64][PPAD]),
// aliased over the A-slab (dead after MFMA_own; barrier-protected).
__global__ __launch_bounds__(256, 1) void lstm_pipe(
    const bf16* __restrict__ x_bf,     // [T*B, D] layer-0 input slabs
    const bf16* __restrict__ h0_all,   // [L, B*H] initial h (bf16)
    const float* __restrict__ c0_all,  // [L, B*H] initial c (f32)
    const bf16* __restrict__ wih,      // [L, 4H, H]
    const bf16* __restrict__ whh,      // [L, 4H, H]
    const float* __restrict__ bias,    // [L, 4H]
    bf16* __restrict__ hseq_base,      // [L, T*B, H]
    float* __restrict__ outH, float* __restrict__ outC,  // [L, B*H]
    int* __restrict__ flags,           // [256] step counters, zeroed
    int* __restrict__ mbox)            // [256*16] 64B-strided mailboxes, zeroed
{
    // A-slab (132 KB) with the partial-sum exchange buffer P aliased on top.
    __shared__ __align__(16) unsigned char smem_raw[64 * APAD * 2];
    bf16*  As = (bf16*)smem_raw;
    float* P  = (float*)smem_raw;      // [4][64][PPAD] = 69.6 KB, alias

    const int tid = threadIdx.x;
    const int wave = tid >> 6, lane = tid & 63;
    const int lmod = lane & 15, lhalf = lane >> 4;
    const int bid = blockIdx.x;
    const int layer = bid >> 6;
    const int j0 = (bid & 63) * 16;
    const bool isAgg = ((bid & 63) == 0);

    const size_t SLAB = (size_t)TT * BB * HH;
    const bf16* inseq = (layer == 0) ? x_bf : (hseq_base + (size_t)(layer - 1) * SLAB);
    bf16* hseq = hseq_base + (size_t)layer * SLAB;
    const bf16* h0 = h0_all + (size_t)layer * BB * HH;
    const float* c0 = c0_all + (size_t)layer * BB * HH;
    float* oH = outH + (size_t)layer * BB * HH;
    float* oC = outC + (size_t)layer * BB * HH;

    // persistent weight fragments, K-split: wave's K-cols = wave*256 + kc*32
    // + lhalf*8; row = gate nt, unit j0+lmod.
    bf16x8 wI[4][8], wH[4][8];
    {
        const size_t lbase = (size_t)layer * FOURH;
#pragma unroll
        for (int nt = 0; nt < 4; nt++) {
            const bf16* rI = wih + (lbase + nt * 1024 + j0 + lmod) * 1024
                                 + wave * 256 + lhalf * 8;
            const bf16* rH = whh + (lbase + nt * 1024 + j0 + lmod) * 1024
                                 + wave * 256 + lhalf * 8;
#pragma unroll
            for (int kc = 0; kc < 8; kc++) {
                wI[nt][kc] = *(const bf16x8*)(rI + kc * 32);
                wH[nt][kc] = *(const bf16x8*)(rH + kc * 32);
            }
        }
    }

    // per-thread gate biases for the cell update: jj is q-invariant (512%16==0)
    const int jj0 = (tid * 2) & 15;
    float bj[4][2];
#pragma unroll
    for (int g = 0; g < 4; g++) {
        bj[g][0] = bias[layer * FOURH + g * 1024 + j0 + jj0];
        bj[g][1] = bias[layer * FOURH + g * 1024 + j0 + jj0 + 1];
    }

    // persistent cell state: thread owns (m, jj0) and (m, jj0+1) at p=q*512+tid*2
    float2 creg[2];
#pragma unroll
    for (int q = 0; q < 2; q++) {
        int p = q * 512 + tid * 2;
        creg[q] = *(const float2*)&c0[(p >> 4) * 1024 + j0 + (p & 15)];
    }

    // cached 16B wave-level staging into padded LDS (global_load_lds).
    auto stage = [&](const bf16* src) {
#pragma unroll
        for (int i = 0; i < 32; i++) {
            int k = wave * 32 + i;
            int row = k >> 1, half = k & 1;
            async_load16(src + (size_t)row * 1024 + half * 512 + lane * 8,
                         &As[row * APAD + half * 512 + lane * 8]);
        }
    };

    for (int t = 0; t < TT; t++) {
        // ---- round start: aggregator gather+fanout; consumers' in-wait ----
        if (wave == 0) {
            if (isAgg && t > 0) {
                for (;;) {
                    int v = aload(&flags[layer * 64 + lane]);
                    if (__all(v >= t)) break;
                }
                astore(&mbox[(layer * 64 + lane) * 16 + 0], t);
                if (layer < 3)
                    astore(&mbox[((layer + 1) * 64 + lane) * 16 + 1], t);
            }
            if (layer > 0 && lane == 0) {
                while (aload(&mbox[bid * 16 + 1]) < t + 1) {}
            }
        }
        __syncthreads();

        // ---- stage input slab h_{l-1,t} (or x_t), cached + L2-shared ----
        stage(inseq + (size_t)t * (BB * HH));
        __syncthreads();

        // ---- input projection MFMA over this wave's K-slice ----
        f32x4 acc[4][4] = {};
#pragma unroll
        for (int kc = 0; kc < 8; kc++) {
            bf16x8 af[4];
#pragma unroll
            for (int mt = 0; mt < 4; mt++)
                af[mt] = *(const bf16x8*)&As[(mt * 16 + lmod) * APAD
                                             + wave * 256 + kc * 32 + lhalf * 8];
#pragma unroll
            for (int mt = 0; mt < 4; mt++)
#pragma unroll
                for (int nt = 0; nt < 4; nt++)
                    acc[mt][nt] = mfma_bf16(af[mt], wI[nt][kc], acc[mt][nt]);
        }

        // ---- own-peer wait (hidden under the input-side work above) ----
        if (wave == 0 && !isAgg && t > 0 && lane == 0) {
            while (aload(&mbox[bid * 16 + 0]) < t) {}
        }
        __syncthreads();   // all waves done reading As; own-dependency cleared

        // ---- stage own h_{t-1} slab ----
        stage((t == 0) ? h0 : (hseq + (size_t)(t - 1) * BB * HH));
        __syncthreads();

        // ---- recurrent MFMA (accumulates onto input projection) ----
#pragma unroll
        for (int kc = 0; kc < 8; kc++) {
            bf16x8 af[4];
#pragma unroll
            for (int mt = 0; mt < 4; mt++)
                af[mt] = *(const bf16x8*)&As[(mt * 16 + lmod) * APAD
                                             + wave * 256 + kc * 32 + lhalf * 8];
#pragma unroll
            for (int mt = 0; mt < 4; mt++)
#pragma unroll
                for (int nt = 0; nt < 4; nt++)
                    acc[mt][nt] = mfma_bf16(af[mt], wH[nt][kc], acc[mt][nt]);
        }
        __syncthreads();   // As dead; safe to overwrite with P partials

        // ---- park K-slice partials in P for the cross-wave reduction ----
#pragma unroll
        for (int mt = 0; mt < 4; mt++)
#pragma unroll
            for (int nt = 0; nt < 4; nt++)
#pragma unroll
                for (int rr = 0; rr < 4; rr++) {
                    int m = mt * 16 + lhalf * 4 + rr;
                    P[(wave * 64 + m) * PPAD + nt * 16 + lmod] = acc[mt][nt][rr];
                }
        __syncthreads();

        // fused cell update (sum 4 wave-partials per gate); publish h via
        // sc1 write-through 4B stores
        const bool lastt = (t == TT - 1);
#pragma unroll
        for (int q = 0; q < 2; q++) {
            int p = q * 512 + tid * 2;
            int m = p >> 4, jj = p & 15;
            float gg4[4][2];
#pragma unroll
            for (int g = 0; g < 4; g++) {
                float s0 = bj[g][0], s1 = bj[g][1];
#pragma unroll
                for (int w = 0; w < 4; w++) {
                    float2 pv = *(const float2*)&P[(w * 64 + m) * PPAD + g * 16 + jj];
                    s0 += pv.x; s1 += pv.y;
                }
                gg4[g][0] = s0; gg4[g][1] = s1;
            }
            float cv[2], hv[2];
#pragma unroll
            for (int u = 0; u < 2; u++) {
                float gi = gg4[0][u], gf = gg4[1][u], gc = gg4[2][u], go = gg4[3][u];
                float cprev = u ? creg[q].y : creg[q].x;
                float c = fsig(gf) * cprev + fsig(gi) * ftanh(gc);
                float h = fsig(go) * ftanh(c);
                cv[u] = c; hv[u] = h;
            }
            creg[q].x = cv[0]; creg[q].y = cv[1];
            union { bf16x2 h2; unsigned int u32; } pk;
            pk.h2.x = (bf16)hv[0]; pk.h2.y = (bf16)hv[1];
            __hip_atomic_store(
                (unsigned int*)&hseq[((size_t)(t * BB + m)) * HH + j0 + jj],
                pk.u32, __ATOMIC_RELAXED, __HIP_MEMORY_SCOPE_AGENT);
            if (lastt) {
                *(float2*)&oH[m * 1024 + j0 + jj] = make_float2(hv[0], hv[1]);
                *(float2*)&oC[m * 1024 + j0 + jj] = make_float2(cv[0], cv[1]);
            }
        }

        // publish: __syncthreads drains each wave's vmcnt (stores are at the
        // coherence point), then one flag store.
        __syncthreads();
        if (tid == 0) astore(&flags[bid], t + 1);
    }

    // ---- deadlock fix: final .in=TT fanout for the next layer's last step ----
    if (wave == 0 && isAgg && layer < 3) {
        for (;;) {
            int v = aload(&flags[layer * 64 + lane]);
            if (__all(v >= TT)) break;
        }
        astore(&mbox[((layer + 1) * 64 + lane) * 16 + 1], TT);
    }
}

extern "C" void kernel_launch(void* const* d_in, const int* in_sizes, int n_in,
                              void* d_out, int out_size, void* d_ws, size_t ws_size,
                              hipStream_t stream) {
    const float* x    = (const float*)d_in[0];
    const float* h0   = (const float*)d_in[1];
    const float* c0   = (const float*)d_in[2];
    const float* Wih  = (const float*)d_in[3];
    const float* Whh  = (const float*)d_in[4];
    const float* bias = (const float*)d_in[5];
    const float* Wout = (const float*)d_in[6];
    const float* bout = (const float*)d_in[7];

    // ---- workspace layout (~226.6 MB) ----
    char* p = (char*)d_ws;
    int*  ctrs    = (int*)p;  p += 1024;                             // 256 flags
    int*  mbox    = (int*)p;  p += 256 * 64;                         // 16 KB mailboxes
    bf16* x_bf    = (bf16*)p; p += (size_t)BB * TT * DD * 2;         // 32 MB ([T][B][D])
    bf16* hseq    = (bf16*)p; p += (size_t)LL * BB * TT * HH * 2;    // 128 MB (per-layer slabs)
    bf16* wih_bf  = (bf16*)p; p += (size_t)LL * FOURH * HH * 2;      // 32 MB
    bf16* whh_bf  = (bf16*)p; p += (size_t)LL * FOURH * HH * 2;      // 32 MB
    bf16* wout_bf = (bf16*)p; p += (size_t)DD * HH * 2;              // 2 MB
    bf16* h0_bf   = (bf16*)p; p += (size_t)LL * BB * HH * 2;         // 0.5 MB
    if ((size_t)(p - (char*)d_ws) > ws_size) return;

    hipMemsetAsync(ctrs, 0, 1024 + 256 * 64, stream);

    // ---- convert inputs to bf16 ----
    cvt_x_transpose<<<BB * TT, 256, 0, stream>>>(x, x_bf);
    {
        struct { const float* in; bf16* out; size_t n; } jobs[4] = {
            { Wih,  wih_bf,  (size_t)LL * FOURH * HH },
            { Whh,  whh_bf,  (size_t)LL * FOURH * HH },
            { Wout, wout_bf, (size_t)DD * HH },
            { h0,   h0_bf,   (size_t)LL * BB * HH },
        };
        for (int j = 0; j < 4; j++) {
            int n4 = (int)(jobs[j].n / 4);
            cvt_f32_bf16<<<(n4 + 255) / 256, 256, 0, stream>>>(jobs[j].in, jobs[j].out, n4);
        }
    }

    float* logits = (float*)d_out;
    float* outH = logits + (size_t)BB * TT * DD;
    float* outC = outH + (size_t)LL * BB * HH;

    // ---- all 4 layers, pipelined, one persistent dispatch ----
    lstm_pipe<<<LL * 64, 256, 0, stream>>>(
        x_bf, h0_bf, c0, wih_bf, whh_bf, bias,
        hseq, outH, outC, ctrs, mbox);

    // ---- output projection from layer-3 hidden sequence ----
    dim3 g2(DD / 128, (BB * TT) / 128);
    gemm_bt<false, true><<<g2, 256, 0, stream>>>(
        hseq + (size_t)(LL - 1) * TT * BB * HH, wout_bf, bout, logits,
        BB * TT, DD, HH);
}